// Round 3
// baseline (98.493 us; speedup 1.0000x reference)
//
#include <hip/hip_runtime.h>
#include <hip/hip_bf16.h>
#include <stdint.h>

// X-ray forward projection. Volume 128^3 fp32, detector 179x179, 10 views.
// Inputs fp32/int32: I_rec [1,1,128,128,128], poses [50,3], idx [10].
// Output fp32 flat: projections [10,179,179] then idx [10] as float.
//
// Geometry: vol[c][y][a], c = spatial_x+63.5, y index = plane p, a = spatial_z+63.5.
// Sampled y at plane p is exactly p-0.5 => ty=0.5:
//   contribution(p) = 0.5*(bilin(slice p-1) + bilin(slice p)) = 0.5*bilin(PS[p])
// Ray linear in p: c(p)=cb+p*sx, a(p)=ab+p*sz;  weight dxw = dist(Pd,E)/ey.
//
// Kept: bf16 row-interleaved PS (IL word = {bf16 row ci+1}<<16 | {bf16 row ci};
// ONE uint2 load/step gives all 4 corners), per-wave LDS c-table, running-
// register pad sweep. Fixed floor: harness 0xAA ws re-poison ~44.4us.
//
// R14 PM: temporal p-split across DISPATCHES regressed (launch+setup+RMW
// overhead); L2-residency bought nothing -> not BW-bound.
// R15 PM: 2-deep batch-8 pipeline only 93.8->92.5 -> not chain-latency-bound.
// Budget: proj ~40us ~ 165cyc/step vs ~40cyc VALU issue -> TLP-starved:
// ~128 VGPR tier = 4 waves/SIMD resident x 40cyc = ~160cyc coverage. QED.
//
// R16: attack occupancy. (a) p-sweep split across 2 waves at the wave's own
// midpoint Qm (4 waves/block = 2 rows x 2 p-halves; LDS combine, no atomics,
// single dispatch) -> 10,800 waves = 10.5/SIMD available. (b) pipeline state
// shrunk to BATCH=4 x 2 stages (32 VGPR state) + __launch_bounds__(256,8) to
// hit the <=64-VGPR tier -> 8 waves/SIMD resident (2x latency coverage).

#define DVOL   128
#define RES    179
#define NPROJ  10
#define OUT_PROJ (NPROJ * RES * RES)
#define BATCH  4

#define IL_A   132                    // word cols: ai in [0,132); col a = ai-1
#define IL_C   130                    // word rows: word ci holds padded rows (ci-1, ci)
#define IL_SLAB (IL_C * IL_A)         // 17160 words per p-slab
#define IL_TOT  (DVOL * IL_SLAB)      // 2,196,480 words = 8.79 MB

__device__ __forceinline__ uint32_t bfbits(float v) {
    __hip_bfloat16 h = __float2bfloat16(v);
    return (uint32_t)*(unsigned short*)&h;
}

// ---- IL builder, running-register sweep: word w = pack(b[c=w-1], b[c=w]).
// grid (8 word-ranges, 128 p), 128 threads = cols a 0..127 (ai = a+1).
__global__ __launch_bounds__(128) void pad_kernel(const float* __restrict__ vol,
                                                  uint32_t* __restrict__ il) {
    const int q = blockIdx.x;             // 0..7
    const int p = blockIdx.y;             // 0..127
    const int a = threadIdx.x;            // 0..127 -> ai = a+1
    const int wlo = q * 17;
    const int whi = min(130, wlo + 17);
    uint32_t* slab = il + p * IL_SLAB;

    uint32_t prev = 0;
    {   // c = wlo-1 (row feeding word wlo's low half)
        const int c = wlo - 1;
        if (c >= 0 && c < 128) {
            const float* src = vol + (c << 14) + (p << 7) + a;
            float v = src[0];
            if (p >= 1) v += src[-128];
            prev = bfbits(v);
        }
    }
    #pragma unroll 2
    for (int c = wlo; c < whi; ++c) {     // word w = c
        uint32_t cur = 0;
        if (c < 128) {
            const float* src = vol + (c << 14) + (p << 7) + a;
            float v = src[0];
            if (p >= 1) v += src[-128];
            cur = bfbits(v);
        }
        slab[c * IL_A + (a + 1)] = (cur << 16) | prev;
        prev = cur;
    }
    // boundary cols ai in {0,129,130,131} are zero words
    for (int b = a; b < (whi - wlo) * 4; b += 128) {
        const int w  = wlo + (b >> 2);
        const int bi = b & 3;
        const int ai = (bi == 0) ? 0 : (128 + bi);   // 0,129,130,131
        slab[w * IL_A + ai] = 0u;
    }
}

__device__ __forceinline__ void axis_interval(float base, float slope, float lo, float hi,
                                              float& t0, float& t1) {
    if (fabsf(slope) < 1e-9f) {
        const bool in = (base >= lo && base <= hi);
        t0 = in ? -1e30f : 1e30f;
        t1 = in ?  1e30f : -1e30f;
    } else {
        const float inv = 1.0f / slope;
        const float a = (lo - base) * inv;
        const float b = (hi - base) * inv;
        t0 = fminf(a, b);
        t1 = fmaxf(a, b);
    }
}

__device__ __forceinline__ int wave_imin(int v) {
    #pragma unroll
    for (int o = 32; o; o >>= 1) v = min(v, __shfl_xor(v, o, 64));
    return v;
}
__device__ __forceinline__ int wave_imax(int v) {
    #pragma unroll
    for (int o = 32; o; o >>= 1) v = max(v, __shfl_xor(v, o, 64));
    return v;
}

__device__ __forceinline__ float asf(uint32_t u) { return __uint_as_float(u); }

// Issue: table read + a-side addr + global uint2 load into named stage regs.
#define ISSUE(tc_, ta_, w_, b_) do {                                          \
    const int base_ = (b_) * BATCH;                                           \
    const float afb_ = fmaf((float)base_, sz, af0);                           \
    _Pragma("unroll")                                                         \
    for (int k = 0; k < BATCH; ++k) {                                         \
        const uint2 t = tab[wid][base_ + k];        /* broadcast ds_read */   \
        tc_[k] = asf(t.x);                                                    \
        const float afc = fminf(fmaxf(fmaf((float)k, sz, afb_), -1.0f), 128.0f);\
        const float a0f = floorf(afc);                                        \
        ta_[k] = afc - a0f;                                                   \
        w_[k] = *(const uint2*)(il + t.y + (int)a0f);                         \
    }                                                                         \
} while (0)

#define CONSUME(tc_, ta_, w_) do {                                            \
    _Pragma("unroll")                                                         \
    for (int k = 0; k < BATCH; ++k) {                                         \
        const float f00 = asf(w_[k].x << 16);          /* row c0,   col a0   */\
        const float f10 = asf(w_[k].x & 0xffff0000u);  /* row c0+1, col a0   */\
        const float f01 = asf(w_[k].y << 16);          /* row c0,   col a0+1 */\
        const float f11 = asf(w_[k].y & 0xffff0000u);  /* row c0+1, col a0+1 */\
        const float h0 = fmaf(ta_[k], f01 - f00, f00);                        \
        const float h1 = fmaf(ta_[k], f11 - f10, f10);                        \
        acc += fmaf(tc_[k], h1 - h0, h0);                                     \
    }                                                                         \
} while (0)

__global__ __launch_bounds__(256, 8) void proj_fast(
    const uint32_t* __restrict__ il,  // IL [128][130][132] packed bf16 pairs
    const float* __restrict__ poses,  // [50,3]
    const int* __restrict__ idx,      // [10]
    float* __restrict__ out)          // [10,179,179] + [10] tail
{
    // per-wave c-side table (each wave's p-half is <=64 steps) + row combine
    __shared__ uint2 tab[4][64];
    __shared__ float red[2][64];

    const int lane = threadIdx.x & 63;
    const int wid  = threadIdx.x >> 6;      // 4 waves/block
    const int rs   = wid & 1;               // row slot within block
    const int h    = wid >> 1;              // p-half: 0 = [Q0,Qm), 1 = [Qm,Q1)
    int gj = blockIdx.x * 64 + lane;        // detector col -> contiguous a
    int gi = blockIdx.y * 2 + rs;           // detector row (wave-uniform)
    const int j = blockIdx.z;

    if (blockIdx.x == 0 && blockIdx.y == 0 && j == 0 && threadIdx.x < NPROJ)
        out[OUT_PROJ + threadIdx.x] = (float)idx[threadIdx.x];

    const bool store_ok = (gi < RES) && (gj < RES);
    gi = min(gi, RES - 1);   // stays wave-uniform
    gj = min(gj, RES - 1);   // dup lanes compute duplicates, store masked

    const int pid = idx[j];
    const float ex = poses[pid * 3 + 0];
    const float ey = poses[pid * 3 + 1];    // [256,384)
    const float ez = poses[pid * 3 + 2];

    const float pdx = (float)gi - 89.5f;
    const float pdz = (float)gj - 89.5f;

    const float inv_ey = 1.0f / ey;
    const float sx = (ex - pdx) * inv_ey;   // wave-uniform
    const float sz = (ez - pdz) * inv_ey;   // per-lane
    const float ddx = pdx - ex, ddz = pdz - ez;
    const float dxw = sqrtf(ddx * ddx + ey * ey + ddz * ddz) * fabsf(inv_ey);
    const float cb = pdx + 63.5f;           // wave-uniform
    const float ab = pdz + 63.5f;

    // Guard trim (conservative superset of nonzero steps), wave-uniform.
    float gc0, gc1, ga0, ga1;
    axis_interval(cb, sx, -1.0f, 128.0f, gc0, gc1);
    axis_interval(ab, sz, -1.0f, 128.0f, ga0, ga1);
    const float q_lo = fmaxf(fmaxf(gc0, ga0), 0.0f);
    const float q_hi = fminf(fminf(gc1, ga1), 127.0f);
    int q0, q1;
    if (q_lo <= q_hi + 0.5f) {
        q0 = max(0, (int)ceilf(q_lo) - 1);
        q1 = min(DVOL, (int)floorf(q_hi) + 2);
    } else { q0 = DVOL; q1 = 0; }           // miss lane: neutral for reduce
    int Q0 = wave_imin(q0);
    int Q1 = wave_imax(q1);
    Q0 = __builtin_amdgcn_readfirstlane(Q0);
    Q1 = __builtin_amdgcn_readfirstlane(Q1);

    // R16: this wave takes half the p-range, split at the wave's midpoint.
    // (Both row-waves compute identical Q0/Q1 -> identical Qm.)
    const int Qm = (Q0 + Q1) >> 1;
    const int lo = h ? Qm : Q0;
    const int hi = h ? Q1 : Qm;
    const int n  = hi - lo;                 // <= 64; may be <= 0

    // Build the wave's c-side table: entry e = p-lo for p in [lo,hi).
    // Wave-local (lanes write, same wave reads) -> no barrier needed here.
    for (int e = lane; e < n; e += 64) {
        const int p = lo + e;
        const float cfc = fminf(fmaxf(fmaf((float)p, sx, cb), -1.0f), 128.0f);
        const float c0f = floorf(cfc);
        const int c0 = (int)c0f;
        uint2 t;
        t.x = __float_as_uint(cfc - c0f);                        // tc
        t.y = (uint32_t)(p * IL_SLAB + (c0 + 1) * IL_A + 1);     // word offset
        tab[wid][e] = t;
    }

    float acc = 0.0f;
    const float af0 = fmaf((float)lo, sz, ab);

    // ---- 2-deep pipelined batch loop: stages A/B, 8 loads in flight ----
    float tcA[BATCH], taA[BATCH]; uint2 wA[BATCH];
    float tcB[BATCH], taB[BATCH]; uint2 wB[BATCH];

    const int nb = (n > 0) ? (n >> 2) : 0;   // full batches of 4
    if (nb >= 2) {
        ISSUE(tcA, taA, wA, 0);
        int b = 0;
        for (; b + 2 < nb; b += 2) {
            ISSUE(tcB, taB, wB, b + 1);
            CONSUME(tcA, taA, wA);           // batch b
            ISSUE(tcA, taA, wA, b + 2);
            CONSUME(tcB, taB, wB);           // batch b+1
        }
        if (b + 1 < nb) {                    // two batches left: b, b+1
            ISSUE(tcB, taB, wB, b + 1);
            CONSUME(tcA, taA, wA);
            CONSUME(tcB, taB, wB);
        } else {                             // one batch left: b
            CONSUME(tcA, taA, wA);
        }
    } else if (nb == 1) {
        ISSUE(tcA, taA, wA, 0);
        CONSUME(tcA, taA, wA);
    }

    // ---- remainder (< 4 steps) ----
    for (int pe = nb << 2; pe < n; ++pe) {
        const uint2 t = tab[wid][pe];
        const float tc = asf(t.x);
        const float afc = fminf(fmaxf(fmaf((float)pe, sz, af0), -1.0f), 128.0f);
        const float a0f = floorf(afc);
        const float ta = afc - a0f;
        const uint2 w2 = *(const uint2*)(il + t.y + (int)a0f);
        const float f00 = asf(w2.x << 16);
        const float f10 = asf(w2.x & 0xffff0000u);
        const float f01 = asf(w2.y << 16);
        const float f11 = asf(w2.y & 0xffff0000u);
        const float h0 = fmaf(ta, f01 - f00, f00);
        const float h1 = fmaf(ta, f11 - f10, f10);
        acc += fmaf(tc, h1 - h0, h0);
    }

    // ---- combine the two p-halves of each row (LDS, one barrier) ----
    if (h == 1) red[rs][lane] = acc;
    __syncthreads();
    if (h == 0 && store_ok)
        out[j * (RES * RES) + gi * RES + gj] = (acc + red[rs][lane]) * (0.5f * dxw);
}

// ---------- fallback (R3-proven, used only if ws too small) ----------
__global__ __launch_bounds__(256) void proj_kernel_fb(
    const float* __restrict__ vol, const float* __restrict__ poses,
    const int* __restrict__ idx, float* __restrict__ out)
{
    const int gj = blockIdx.x * 64 + (threadIdx.x & 63);
    const int gi = blockIdx.y * 4 + (threadIdx.x >> 6);
    const int j  = blockIdx.z;
    if (blockIdx.x == 0 && blockIdx.y == 0 && j == 0 && threadIdx.x < NPROJ)
        out[OUT_PROJ + threadIdx.x] = (float)idx[threadIdx.x];
    if (gi >= RES || gj >= RES) return;
    const int pid = idx[j];
    const float ex = poses[pid*3+0], ey = poses[pid*3+1], ez = poses[pid*3+2];
    const float pdx = (float)gi - 89.5f, pdz = (float)gj - 89.5f;
    const float inv_ey = 1.0f / ey;
    const float sx = (ex - pdx) * inv_ey, sz = (ez - pdz) * inv_ey;
    const float ddx = pdx - ex, ddz = pdz - ez;
    const float dxw = sqrtf(ddx*ddx + ey*ey + ddz*ddz) * fabsf(inv_ey);
    const float cb = pdx + 63.5f, ab = pdz + 63.5f;
    float acc = 0.0f;
    for (int p = 0; p < DVOL; ++p) {
        const float cf = fmaf((float)p, sx, cb);
        const float af = fmaf((float)p, sz, ab);
        if (cf >= -1.0f && cf < 128.0f && af >= -1.0f && af < 128.0f) {
            const float c0f = floorf(cf), a0f = floorf(af);
            const float tc = cf - c0f, ta = af - a0f;
            const int c0 = (int)c0f, a0 = (int)a0f;
            const float wc0 = (c0 >= 0)   ? (1.0f - tc) : 0.0f;
            const float wc1 = (c0 <= 126) ? tc          : 0.0f;
            const float wa0 = (a0 >= 0)   ? (1.0f - ta) : 0.0f;
            const float wa1 = (a0 <= 126) ? ta          : 0.0f;
            const int c0c = c0 < 0 ? 0 : c0;
            const int c1c = c0 >= 127 ? 127 : c0 + 1;
            const int a0c = a0 < 0 ? 0 : a0;
            const int a1c = a0 >= 127 ? 127 : a0 + 1;
            const float w00 = wc0*wa0, w01 = wc0*wa1, w10 = wc1*wa0, w11 = wc1*wa1;
            const int b0 = (c0c << 14) + (p << 7);
            const int b1 = (c1c << 14) + (p << 7);
            float s = w00*vol[b0+a0c] + w01*vol[b0+a1c] + w10*vol[b1+a0c] + w11*vol[b1+a1c];
            if (p >= 1)
                s += w00*vol[b0+a0c-128] + w01*vol[b0+a1c-128]
                   + w10*vol[b1+a0c-128] + w11*vol[b1+a1c-128];
            acc += 0.5f * s;
        }
    }
    out[j * (RES * RES) + gi * RES + gj] = acc * dxw;
}

extern "C" void kernel_launch(void* const* d_in, const int* in_sizes, int n_in,
                              void* d_out, int out_size, void* d_ws, size_t ws_size,
                              hipStream_t stream) {
    const float* vol   = (const float*)d_in[0];
    const float* poses = (const float*)d_in[1];
    const int*   idx   = (const int*)d_in[2];
    float* out = (float*)d_out;

    if (ws_size >= (size_t)IL_TOT * sizeof(uint32_t)) {
        uint32_t* ilbuf = (uint32_t*)d_ws;
        dim3 pgrid(8, DVOL);                                        // (word-range, p)
        pad_kernel<<<pgrid, 128, 0, stream>>>(vol, ilbuf);
        dim3 grid(3 /*ceil(179/64)*/, 90 /*ceil(179/2)*/, NPROJ);   // 2 rows x 2 p-halves
        proj_fast<<<grid, 256, 0, stream>>>(ilbuf, poses, idx, out);
    } else {
        dim3 grid(3, 45, NPROJ);
        proj_kernel_fb<<<grid, 256, 0, stream>>>(vol, poses, idx, out);
    }
}

// Round 4
// 97.899 us; speedup vs baseline: 1.0061x; 1.0061x over previous
//
#include <hip/hip_runtime.h>
#include <hip/hip_bf16.h>
#include <stdint.h>

// X-ray forward projection. Volume 128^3 fp32, detector 179x179, 10 views.
// Inputs fp32/int32: I_rec [1,1,128,128,128], poses [50,3], idx [10].
// Output fp32 flat: projections [10,179,179] then idx [10] as float.
//
// Geometry: vol[c][y][a], c = spatial_x+63.5, y index = plane p, a = spatial_z+63.5.
// Sampled y at plane p is exactly p-0.5 => ty=0.5:
//   contribution(p) = 0.5*(bilin(slice p-1) + bilin(slice p)) = 0.5*bilin(PS[p])
// Ray linear in p: c(p)=cb+p*sx, a(p)=ab+p*sz;  weight dxw = dist(Pd,E)/ey.
//
// Kept: bf16 row-interleaved PS (IL word = {bf16 row ci+1}<<16 | {bf16 row ci};
// ONE uint2 load/step gives all 4 corners), running-register pad sweep.
// Fixed floor: harness 0xAA ws re-poison ~44.4us.
//
// R14 PM: dispatch-level p-split regressed; L2 residency bought nothing.
// R15 PM: 2-deep batch-8 pipeline 93.8->92.5 only -> lgkm chain inside ISSUE
//   (ds_read tab -> wait -> addr -> global_load) eats the prefetch distance.
// R16 PM: launch_bounds(256,8) forced 64-VGPR cap on ~80-VGPR kernel ->
//   spills -> 98.5. Also: occupancy tiers step only at 64/128/256 VGPR, so
//   the 85-VGPR/6-wave target doesn't exist; (64,128] is always 4 waves/SIMD.
//
// R17: DELETE the LDS c-table. Compute c-side inline (~9 VALU/step: fma+
// clamp+floor+cvt + int mad for word offset) -> load address depends only on
// VALU, no lgkm wait in the chain. Keep wave p-split (2 rows x 2 p-halves,
// 10740 waves, finer SIMD load balance) with NATURAL regalloc (~80 VGPR,
// <=128 tier, no spills). LDS: 512B combine buffer only.

#define DVOL   128
#define RES    179
#define NPROJ  10
#define OUT_PROJ (NPROJ * RES * RES)
#define BATCH  4

#define IL_A   132                    // word cols: ai in [0,132); col a = ai-1
#define IL_C   130                    // word rows: word ci holds padded rows (ci-1, ci)
#define IL_SLAB (IL_C * IL_A)         // 17160 words per p-slab
#define IL_TOT  (DVOL * IL_SLAB)      // 2,196,480 words = 8.79 MB

__device__ __forceinline__ uint32_t bfbits(float v) {
    __hip_bfloat16 h = __float2bfloat16(v);
    return (uint32_t)*(unsigned short*)&h;
}

// ---- IL builder, running-register sweep: word w = pack(b[c=w-1], b[c=w]).
// grid (8 word-ranges, 128 p), 128 threads = cols a 0..127 (ai = a+1).
__global__ __launch_bounds__(128) void pad_kernel(const float* __restrict__ vol,
                                                  uint32_t* __restrict__ il) {
    const int q = blockIdx.x;             // 0..7
    const int p = blockIdx.y;             // 0..127
    const int a = threadIdx.x;            // 0..127 -> ai = a+1
    const int wlo = q * 17;
    const int whi = min(130, wlo + 17);
    uint32_t* slab = il + p * IL_SLAB;

    uint32_t prev = 0;
    {   // c = wlo-1 (row feeding word wlo's low half)
        const int c = wlo - 1;
        if (c >= 0 && c < 128) {
            const float* src = vol + (c << 14) + (p << 7) + a;
            float v = src[0];
            if (p >= 1) v += src[-128];
            prev = bfbits(v);
        }
    }
    #pragma unroll 2
    for (int c = wlo; c < whi; ++c) {     // word w = c
        uint32_t cur = 0;
        if (c < 128) {
            const float* src = vol + (c << 14) + (p << 7) + a;
            float v = src[0];
            if (p >= 1) v += src[-128];
            cur = bfbits(v);
        }
        slab[c * IL_A + (a + 1)] = (cur << 16) | prev;
        prev = cur;
    }
    // boundary cols ai in {0,129,130,131} are zero words
    for (int b = a; b < (whi - wlo) * 4; b += 128) {
        const int w  = wlo + (b >> 2);
        const int bi = b & 3;
        const int ai = (bi == 0) ? 0 : (128 + bi);   // 0,129,130,131
        slab[w * IL_A + ai] = 0u;
    }
}

__device__ __forceinline__ void axis_interval(float base, float slope, float lo, float hi,
                                              float& t0, float& t1) {
    if (fabsf(slope) < 1e-9f) {
        const bool in = (base >= lo && base <= hi);
        t0 = in ? -1e30f : 1e30f;
        t1 = in ?  1e30f : -1e30f;
    } else {
        const float inv = 1.0f / slope;
        const float a = (lo - base) * inv;
        const float b = (hi - base) * inv;
        t0 = fminf(a, b);
        t1 = fmaxf(a, b);
    }
}

__device__ __forceinline__ int wave_imin(int v) {
    #pragma unroll
    for (int o = 32; o; o >>= 1) v = min(v, __shfl_xor(v, o, 64));
    return v;
}
__device__ __forceinline__ int wave_imax(int v) {
    #pragma unroll
    for (int o = 32; o; o >>= 1) v = max(v, __shfl_xor(v, o, 64));
    return v;
}

__device__ __forceinline__ float asf(uint32_t u) { return __uint_as_float(u); }

// Issue: inline c-side + a-side addr compute (pure VALU) + global uint2 load.
// Word offset for step p: p*IL_SLAB + (c0+1)*IL_A + 1 + a0, c0,a0 in [-1,128].
#define ISSUE(tc_, ta_, w_, b_) do {                                          \
    const int base_ = (b_) * BATCH;                                           \
    const float afb_ = fmaf((float)base_, sz, af0);                           \
    const float cfb_ = fmaf((float)base_, sx, cf0);                           \
    const int   pw_  = (lo + base_) * IL_SLAB + IL_A + 1;                     \
    _Pragma("unroll")                                                         \
    for (int k = 0; k < BATCH; ++k) {                                         \
        const float cfc = fminf(fmaxf(fmaf((float)k, sx, cfb_), -1.0f), 128.0f);\
        const float c0f = floorf(cfc);                                        \
        tc_[k] = cfc - c0f;                                                   \
        const float afc = fminf(fmaxf(fmaf((float)k, sz, afb_), -1.0f), 128.0f);\
        const float a0f = floorf(afc);                                        \
        ta_[k] = afc - a0f;                                                   \
        const int off = pw_ + k * IL_SLAB + ((int)c0f) * IL_A + (int)a0f;     \
        w_[k] = *(const uint2*)(il + off);                                    \
    }                                                                         \
} while (0)

#define CONSUME(tc_, ta_, w_) do {                                            \
    _Pragma("unroll")                                                         \
    for (int k = 0; k < BATCH; ++k) {                                         \
        const float f00 = asf(w_[k].x << 16);          /* row c0,   col a0   */\
        const float f10 = asf(w_[k].x & 0xffff0000u);  /* row c0+1, col a0   */\
        const float f01 = asf(w_[k].y << 16);          /* row c0,   col a0+1 */\
        const float f11 = asf(w_[k].y & 0xffff0000u);  /* row c0+1, col a0+1 */\
        const float h0 = fmaf(ta_[k], f01 - f00, f00);                        \
        const float h1 = fmaf(ta_[k], f11 - f10, f10);                        \
        acc += fmaf(tc_[k], h1 - h0, h0);                                     \
    }                                                                         \
} while (0)

__global__ __launch_bounds__(256) void proj_fast(
    const uint32_t* __restrict__ il,  // IL [128][130][132] packed bf16 pairs
    const float* __restrict__ poses,  // [50,3]
    const int* __restrict__ idx,      // [10]
    float* __restrict__ out)          // [10,179,179] + [10] tail
{
    __shared__ float red[2][64];            // p-half combine per row slot

    const int lane = threadIdx.x & 63;
    const int wid  = threadIdx.x >> 6;      // 4 waves/block
    const int rs   = wid & 1;               // row slot within block
    const int h    = wid >> 1;              // p-half: 0 = [Q0,Qm), 1 = [Qm,Q1)
    int gj = blockIdx.x * 64 + lane;        // detector col -> contiguous a
    int gi = blockIdx.y * 2 + rs;           // detector row (wave-uniform)
    const int j = blockIdx.z;

    if (blockIdx.x == 0 && blockIdx.y == 0 && j == 0 && threadIdx.x < NPROJ)
        out[OUT_PROJ + threadIdx.x] = (float)idx[threadIdx.x];

    const bool store_ok = (gi < RES) && (gj < RES);
    gi = min(gi, RES - 1);   // stays wave-uniform
    gj = min(gj, RES - 1);   // dup lanes compute duplicates, store masked

    const int pid = idx[j];
    const float ex = poses[pid * 3 + 0];
    const float ey = poses[pid * 3 + 1];    // [256,384)
    const float ez = poses[pid * 3 + 2];

    const float pdx = (float)gi - 89.5f;
    const float pdz = (float)gj - 89.5f;

    const float inv_ey = 1.0f / ey;
    const float sx = (ex - pdx) * inv_ey;   // wave-uniform
    const float sz = (ez - pdz) * inv_ey;   // per-lane
    const float ddx = pdx - ex, ddz = pdz - ez;
    const float dxw = sqrtf(ddx * ddx + ey * ey + ddz * ddz) * fabsf(inv_ey);
    const float cb = pdx + 63.5f;           // wave-uniform
    const float ab = pdz + 63.5f;

    // Guard trim (conservative superset of nonzero steps), wave-uniform.
    float gc0, gc1, ga0, ga1;
    axis_interval(cb, sx, -1.0f, 128.0f, gc0, gc1);
    axis_interval(ab, sz, -1.0f, 128.0f, ga0, ga1);
    const float q_lo = fmaxf(fmaxf(gc0, ga0), 0.0f);
    const float q_hi = fminf(fminf(gc1, ga1), 127.0f);
    int q0, q1;
    if (q_lo <= q_hi + 0.5f) {
        q0 = max(0, (int)ceilf(q_lo) - 1);
        q1 = min(DVOL, (int)floorf(q_hi) + 2);
    } else { q0 = DVOL; q1 = 0; }           // miss lane: neutral for reduce
    int Q0 = wave_imin(q0);
    int Q1 = wave_imax(q1);
    Q0 = __builtin_amdgcn_readfirstlane(Q0);
    Q1 = __builtin_amdgcn_readfirstlane(Q1);

    // Wave takes half the p-range, split at the wave's midpoint. Row-partner
    // waves (same rs, h=0/1) have identical gi -> identical Q0/Q1/Qm.
    const int Qm = (Q0 + Q1) >> 1;
    const int lo = h ? Qm : Q0;
    const int hi = h ? Q1 : Qm;
    const int n  = hi - lo;                 // <= 64; may be <= 0

    float acc = 0.0f;
    const float af0 = fmaf((float)lo, sz, ab);
    const float cf0 = fmaf((float)lo, sx, cb);

    // ---- 2-deep pipelined batch loop: stages A/B, 8 loads in flight ----
    float tcA[BATCH], taA[BATCH]; uint2 wA[BATCH];
    float tcB[BATCH], taB[BATCH]; uint2 wB[BATCH];

    const int nb = (n > 0) ? (n >> 2) : 0;   // full batches of 4
    if (nb >= 2) {
        ISSUE(tcA, taA, wA, 0);
        int b = 0;
        for (; b + 2 < nb; b += 2) {
            ISSUE(tcB, taB, wB, b + 1);
            CONSUME(tcA, taA, wA);           // batch b
            ISSUE(tcA, taA, wA, b + 2);
            CONSUME(tcB, taB, wB);           // batch b+1
        }
        if (b + 1 < nb) {                    // two batches left: b, b+1
            ISSUE(tcB, taB, wB, b + 1);
            CONSUME(tcA, taA, wA);
            CONSUME(tcB, taB, wB);
        } else {                             // one batch left: b
            CONSUME(tcA, taA, wA);
        }
    } else if (nb == 1) {
        ISSUE(tcA, taA, wA, 0);
        CONSUME(tcA, taA, wA);
    }

    // ---- remainder (< 4 steps) ----
    for (int pe = nb << 2; pe < n; ++pe) {
        const float cfc = fminf(fmaxf(fmaf((float)pe, sx, cf0), -1.0f), 128.0f);
        const float c0f = floorf(cfc);
        const float tc = cfc - c0f;
        const float afc = fminf(fmaxf(fmaf((float)pe, sz, af0), -1.0f), 128.0f);
        const float a0f = floorf(afc);
        const float ta = afc - a0f;
        const int off = (lo + pe) * IL_SLAB + ((int)c0f) * IL_A + IL_A + 1 + (int)a0f;
        const uint2 w2 = *(const uint2*)(il + off);
        const float f00 = asf(w2.x << 16);
        const float f10 = asf(w2.x & 0xffff0000u);
        const float f01 = asf(w2.y << 16);
        const float f11 = asf(w2.y & 0xffff0000u);
        const float h0 = fmaf(ta, f01 - f00, f00);
        const float h1 = fmaf(ta, f11 - f10, f10);
        acc += fmaf(tc, h1 - h0, h0);
    }

    // ---- combine the two p-halves of each row (LDS, one barrier) ----
    if (h == 1) red[rs][lane] = acc;
    __syncthreads();
    if (h == 0 && store_ok)
        out[j * (RES * RES) + gi * RES + gj] = (acc + red[rs][lane]) * (0.5f * dxw);
}

// ---------- fallback (R3-proven, used only if ws too small) ----------
__global__ __launch_bounds__(256) void proj_kernel_fb(
    const float* __restrict__ vol, const float* __restrict__ poses,
    const int* __restrict__ idx, float* __restrict__ out)
{
    const int gj = blockIdx.x * 64 + (threadIdx.x & 63);
    const int gi = blockIdx.y * 4 + (threadIdx.x >> 6);
    const int j  = blockIdx.z;
    if (blockIdx.x == 0 && blockIdx.y == 0 && j == 0 && threadIdx.x < NPROJ)
        out[OUT_PROJ + threadIdx.x] = (float)idx[threadIdx.x];
    if (gi >= RES || gj >= RES) return;
    const int pid = idx[j];
    const float ex = poses[pid*3+0], ey = poses[pid*3+1], ez = poses[pid*3+2];
    const float pdx = (float)gi - 89.5f, pdz = (float)gj - 89.5f;
    const float inv_ey = 1.0f / ey;
    const float sx = (ex - pdx) * inv_ey, sz = (ez - pdz) * inv_ey;
    const float ddx = pdx - ex, ddz = pdz - ez;
    const float dxw = sqrtf(ddx*ddx + ey*ey + ddz*ddz) * fabsf(inv_ey);
    const float cb = pdx + 63.5f, ab = pdz + 63.5f;
    float acc = 0.0f;
    for (int p = 0; p < DVOL; ++p) {
        const float cf = fmaf((float)p, sx, cb);
        const float af = fmaf((float)p, sz, ab);
        if (cf >= -1.0f && cf < 128.0f && af >= -1.0f && af < 128.0f) {
            const float c0f = floorf(cf), a0f = floorf(af);
            const float tc = cf - c0f, ta = af - a0f;
            const int c0 = (int)c0f, a0 = (int)a0f;
            const float wc0 = (c0 >= 0)   ? (1.0f - tc) : 0.0f;
            const float wc1 = (c0 <= 126) ? tc          : 0.0f;
            const float wa0 = (a0 >= 0)   ? (1.0f - ta) : 0.0f;
            const float wa1 = (a0 <= 126) ? ta          : 0.0f;
            const int c0c = c0 < 0 ? 0 : c0;
            const int c1c = c0 >= 127 ? 127 : c0 + 1;
            const int a0c = a0 < 0 ? 0 : a0;
            const int a1c = a0 >= 127 ? 127 : a0 + 1;
            const float w00 = wc0*wa0, w01 = wc0*wa1, w10 = wc1*wa0, w11 = wc1*wa1;
            const int b0 = (c0c << 14) + (p << 7);
            const int b1 = (c1c << 14) + (p << 7);
            float s = w00*vol[b0+a0c] + w01*vol[b0+a1c] + w10*vol[b1+a0c] + w11*vol[b1+a1c];
            if (p >= 1)
                s += w00*vol[b0+a0c-128] + w01*vol[b0+a1c-128]
                   + w10*vol[b1+a0c-128] + w11*vol[b1+a1c-128];
            acc += 0.5f * s;
        }
    }
    out[j * (RES * RES) + gi * RES + gj] = acc * dxw;
}

extern "C" void kernel_launch(void* const* d_in, const int* in_sizes, int n_in,
                              void* d_out, int out_size, void* d_ws, size_t ws_size,
                              hipStream_t stream) {
    const float* vol   = (const float*)d_in[0];
    const float* poses = (const float*)d_in[1];
    const int*   idx   = (const int*)d_in[2];
    float* out = (float*)d_out;

    if (ws_size >= (size_t)IL_TOT * sizeof(uint32_t)) {
        uint32_t* ilbuf = (uint32_t*)d_ws;
        dim3 pgrid(8, DVOL);                                        // (word-range, p)
        pad_kernel<<<pgrid, 128, 0, stream>>>(vol, ilbuf);
        dim3 grid(3 /*ceil(179/64)*/, 90 /*ceil(179/2)*/, NPROJ);   // 2 rows x 2 p-halves
        proj_fast<<<grid, 256, 0, stream>>>(ilbuf, poses, idx, out);
    } else {
        dim3 grid(3, 45, NPROJ);
        proj_kernel_fb<<<grid, 256, 0, stream>>>(vol, poses, idx, out);
    }
}

// Round 5
// 91.511 us; speedup vs baseline: 1.0763x; 1.0698x over previous
//
#include <hip/hip_runtime.h>
#include <hip/hip_bf16.h>
#include <stdint.h>

// X-ray forward projection. Volume 128^3 fp32, detector 179x179, 10 views.
// Inputs fp32/int32: I_rec [1,1,128,128,128], poses [50,3], idx [10].
// Output fp32 flat: projections [10,179,179] then idx [10] as float.
//
// Geometry: vol[c][y][a], c = spatial_x+63.5, y index = plane p, a = spatial_z+63.5.
// Sampled y at plane p is exactly p-0.5 => ty=0.5:
//   contribution(p) = 0.5*(bilin(slice p-1) + bilin(slice p)) = 0.5*bilin(PS[p])
// Ray linear in p: c(p)=cb+p*sx, a(p)=ab+p*sz;  weight dxw = dist(Pd,E)/ey.
//
// Kept: bf16 row-interleaved PS (IL word = {bf16 row ci+1}<<16 | {bf16 row ci};
// ONE uint2 load/step gives all 4 corners), per-wave LDS c-table (broadcast
// ds_read_b64/step), 2-deep batch-8 pipeline (R15), grid 3x90x10 x 128thr.
// Fixed floor: harness 0xAA ws re-poison ~44.4us.
//
// DIAGNOSIS (R14-R17 arc): proj = 152 cyc/wave-step = 19 VALU x 2cyc x 4
// resident waves -> SIMD VALU pipe SATURATED. VALU-issue-bound; not latency
// (R15 +1.3 only), not occupancy (R16 spilled; tiers are 64/128/256 only),
// not BW (R14 L2-window null), and inline c-side ADDS VALU (R17 regressed).
// The only lever: fewer VALU instructions per step.
//
// R18: a-side addressing rewrite, -3 VALU/step (19 -> ~16):
//   af pre-biased +1 -> range [0,129]:
//     fmed3(af1, 0, 129)            1 instr clamp (explicit, not min+max)
//     (int)af1                      trunc == floor for af1 >= 0, yields a0+1
//     fract(af1)                    ta directly (no floor+sub)
//   +1 bias folds into table t.y (drops its trailing +1). Everything else
//   is exactly R15 (best so far, 92.5).

#define DVOL   128
#define RES    179
#define NPROJ  10
#define OUT_PROJ (NPROJ * RES * RES)
#define BATCH  8

#define IL_A   132                    // word cols: ai in [0,132); col a = ai-1
#define IL_C   130                    // word rows: word ci holds padded rows (ci-1, ci)
#define IL_SLAB (IL_C * IL_A)         // 17160 words per p-slab
#define IL_TOT  (DVOL * IL_SLAB)      // 2,196,480 words = 8.79 MB

__device__ __forceinline__ uint32_t bfbits(float v) {
    __hip_bfloat16 h = __float2bfloat16(v);
    return (uint32_t)*(unsigned short*)&h;
}

// ---- IL builder, running-register sweep: word w = pack(b[c=w-1], b[c=w]).
// grid (8 word-ranges, 128 p), 128 threads = cols a 0..127 (ai = a+1).
__global__ __launch_bounds__(128) void pad_kernel(const float* __restrict__ vol,
                                                  uint32_t* __restrict__ il) {
    const int q = blockIdx.x;             // 0..7
    const int p = blockIdx.y;             // 0..127
    const int a = threadIdx.x;            // 0..127 -> ai = a+1
    const int wlo = q * 17;
    const int whi = min(130, wlo + 17);
    uint32_t* slab = il + p * IL_SLAB;

    uint32_t prev = 0;
    {   // c = wlo-1 (row feeding word wlo's low half)
        const int c = wlo - 1;
        if (c >= 0 && c < 128) {
            const float* src = vol + (c << 14) + (p << 7) + a;
            float v = src[0];
            if (p >= 1) v += src[-128];
            prev = bfbits(v);
        }
    }
    #pragma unroll 2
    for (int c = wlo; c < whi; ++c) {     // word w = c
        uint32_t cur = 0;
        if (c < 128) {
            const float* src = vol + (c << 14) + (p << 7) + a;
            float v = src[0];
            if (p >= 1) v += src[-128];
            cur = bfbits(v);
        }
        slab[c * IL_A + (a + 1)] = (cur << 16) | prev;
        prev = cur;
    }
    // boundary cols ai in {0,129,130,131} are zero words
    for (int b = a; b < (whi - wlo) * 4; b += 128) {
        const int w  = wlo + (b >> 2);
        const int bi = b & 3;
        const int ai = (bi == 0) ? 0 : (128 + bi);   // 0,129,130,131
        slab[w * IL_A + ai] = 0u;
    }
}

__device__ __forceinline__ void axis_interval(float base, float slope, float lo, float hi,
                                              float& t0, float& t1) {
    if (fabsf(slope) < 1e-9f) {
        const bool in = (base >= lo && base <= hi);
        t0 = in ? -1e30f : 1e30f;
        t1 = in ?  1e30f : -1e30f;
    } else {
        const float inv = 1.0f / slope;
        const float a = (lo - base) * inv;
        const float b = (hi - base) * inv;
        t0 = fminf(a, b);
        t1 = fmaxf(a, b);
    }
}

__device__ __forceinline__ int wave_imin(int v) {
    #pragma unroll
    for (int o = 32; o; o >>= 1) v = min(v, __shfl_xor(v, o, 64));
    return v;
}
__device__ __forceinline__ int wave_imax(int v) {
    #pragma unroll
    for (int o = 32; o; o >>= 1) v = max(v, __shfl_xor(v, o, 64));
    return v;
}

__device__ __forceinline__ float asf(uint32_t u) { return __uint_as_float(u); }

// Issue: table read + a-side addr (5 VALU: fma, med3, cvt, fract, add) +
// global uint2 load. af-coords pre-biased +1 => [0,129]; trunc == floor.
#define ISSUE(tc_, ta_, w_, b_) do {                                          \
    const int base_ = (b_) * BATCH;                                           \
    const float afb_ = fmaf((float)base_, sz, af0);                           \
    _Pragma("unroll")                                                         \
    for (int k = 0; k < BATCH; ++k) {                                         \
        const uint2 t = tab[wid][base_ + k];        /* broadcast ds_read */   \
        tc_[k] = asf(t.x);                                                    \
        const float af1 = __builtin_amdgcn_fmed3f(                            \
            fmaf((float)k, sz, afb_), 0.0f, 129.0f);                          \
        ta_[k] = __builtin_amdgcn_fractf(af1);                                \
        const uint32_t off = t.y + (uint32_t)(int)af1;  /* t.y has no +1 */   \
        w_[k] = *(const uint2*)(il + off);                                    \
    }                                                                         \
} while (0)

#define CONSUME(tc_, ta_, w_) do {                                            \
    _Pragma("unroll")                                                         \
    for (int k = 0; k < BATCH; ++k) {                                         \
        const float f00 = asf(w_[k].x << 16);          /* row c0,   col a0   */\
        const float f10 = asf(w_[k].x & 0xffff0000u);  /* row c0+1, col a0   */\
        const float f01 = asf(w_[k].y << 16);          /* row c0,   col a0+1 */\
        const float f11 = asf(w_[k].y & 0xffff0000u);  /* row c0+1, col a0+1 */\
        const float h0 = fmaf(ta_[k], f01 - f00, f00);                        \
        const float h1 = fmaf(ta_[k], f11 - f10, f10);                        \
        acc += fmaf(tc_[k], h1 - h0, h0);                                     \
    }                                                                         \
} while (0)

__global__ __launch_bounds__(128) void proj_fast(
    const uint32_t* __restrict__ il,  // IL [128][130][132] packed bf16 pairs
    const float* __restrict__ poses,  // [50,3]
    const int* __restrict__ idx,      // [10]
    float* __restrict__ out)          // [10,179,179] + [10] tail
{
    // per-wave c-side table: {tc as bits, word offset sans a-term} per p
    __shared__ uint2 tab[2][DVOL];

    const int lane = threadIdx.x & 63;
    const int wid  = threadIdx.x >> 6;      // 2 waves/block
    int gj = blockIdx.x * 64 + lane;        // detector col -> contiguous a
    int gi = blockIdx.y * 2 + wid;          // detector row (wave-uniform)
    const int j = blockIdx.z;

    if (blockIdx.x == 0 && blockIdx.y == 0 && j == 0 && threadIdx.x < NPROJ)
        out[OUT_PROJ + threadIdx.x] = (float)idx[threadIdx.x];

    const bool store_ok = (gi < RES) && (gj < RES);
    gi = min(gi, RES - 1);   // stays wave-uniform
    gj = min(gj, RES - 1);   // dup lanes compute duplicates, store masked

    const int pid = idx[j];
    const float ex = poses[pid * 3 + 0];
    const float ey = poses[pid * 3 + 1];    // [256,384)
    const float ez = poses[pid * 3 + 2];

    const float pdx = (float)gi - 89.5f;
    const float pdz = (float)gj - 89.5f;

    const float inv_ey = 1.0f / ey;
    const float sx = (ex - pdx) * inv_ey;   // wave-uniform
    const float sz = (ez - pdz) * inv_ey;   // per-lane
    const float ddx = pdx - ex, ddz = pdz - ez;
    const float dxw = sqrtf(ddx * ddx + ey * ey + ddz * ddz) * fabsf(inv_ey);
    const float cb = pdx + 63.5f;           // wave-uniform
    const float ab = pdz + 63.5f;

    // Guard trim (conservative superset of nonzero steps), wave-uniform.
    float gc0, gc1, ga0, ga1;
    axis_interval(cb, sx, -1.0f, 128.0f, gc0, gc1);
    axis_interval(ab, sz, -1.0f, 128.0f, ga0, ga1);
    const float q_lo = fmaxf(fmaxf(gc0, ga0), 0.0f);
    const float q_hi = fminf(fminf(gc1, ga1), 127.0f);
    int q0, q1;
    if (q_lo <= q_hi + 0.5f) {
        q0 = max(0, (int)ceilf(q_lo) - 1);
        q1 = min(DVOL, (int)floorf(q_hi) + 2);
    } else { q0 = DVOL; q1 = 0; }           // miss lane: neutral for reduce
    int Q0 = wave_imin(q0);
    int Q1 = wave_imax(q1);
    Q0 = __builtin_amdgcn_readfirstlane(Q0);
    Q1 = __builtin_amdgcn_readfirstlane(Q1);

    // Build the wave's c-side table: entry e = p-Q0 for p in [Q0,Q1).
    // Same +1-bias trick as the a-side: cf1 in [0,129], trunc == floor,
    // (c0+1) = (int)cf1 folds into the word-row term. t.y drops its +1
    // (the a-side index is a0+1 now).
    const int n = Q1 - Q0;
    for (int e = lane; e < n; e += 64) {
        const int p = Q0 + e;
        const float cf1 = __builtin_amdgcn_fmed3f(
            fmaf((float)p, sx, cb) + 1.0f, 0.0f, 129.0f);
        const int c0i = (int)cf1;                                // = c0+1
        uint2 t;
        t.x = __float_as_uint(__builtin_amdgcn_fractf(cf1));     // tc
        t.y = (uint32_t)(p * IL_SLAB + c0i * IL_A);              // word offset
        tab[wid][e] = t;
    }

    float acc = 0.0f;
    // af pre-biased +1: af0 = ab + 1 + Q0*sz
    const float af0 = fmaf((float)Q0, sz, ab + 1.0f);

    // ---- 2-deep pipelined batch loop: stages A/B, 16 loads in flight ----
    float tcA[BATCH], taA[BATCH]; uint2 wA[BATCH];
    float tcB[BATCH], taB[BATCH]; uint2 wB[BATCH];

    const int nb = (n > 0) ? (n >> 3) : 0;   // full batches of 8
    if (nb >= 2) {
        ISSUE(tcA, taA, wA, 0);
        int b = 0;
        for (; b + 2 < nb; b += 2) {
            ISSUE(tcB, taB, wB, b + 1);
            CONSUME(tcA, taA, wA);           // batch b
            ISSUE(tcA, taA, wA, b + 2);
            CONSUME(tcB, taB, wB);           // batch b+1
        }
        if (b + 1 < nb) {                    // two batches left: b, b+1
            ISSUE(tcB, taB, wB, b + 1);
            CONSUME(tcA, taA, wA);
            CONSUME(tcB, taB, wB);
        } else {                             // one batch left: b
            CONSUME(tcA, taA, wA);
        }
    } else if (nb == 1) {
        ISSUE(tcA, taA, wA, 0);
        CONSUME(tcA, taA, wA);
    }

    // ---- remainder (< 8 steps) ----
    for (int pe = nb << 3; pe < n; ++pe) {
        const uint2 t = tab[wid][pe];
        const float tc = asf(t.x);
        const float af1 = __builtin_amdgcn_fmed3f(
            fmaf((float)pe, sz, af0), 0.0f, 129.0f);
        const float ta = __builtin_amdgcn_fractf(af1);
        const uint32_t off = t.y + (uint32_t)(int)af1;
        const uint2 w2 = *(const uint2*)(il + off);
        const float f00 = asf(w2.x << 16);
        const float f10 = asf(w2.x & 0xffff0000u);
        const float f01 = asf(w2.y << 16);
        const float f11 = asf(w2.y & 0xffff0000u);
        const float h0 = fmaf(ta, f01 - f00, f00);
        const float h1 = fmaf(ta, f11 - f10, f10);
        acc += fmaf(tc, h1 - h0, h0);
    }

    if (store_ok) out[j * (RES * RES) + gi * RES + gj] = acc * (0.5f * dxw);
}

// ---------- fallback (R3-proven, used only if ws too small) ----------
__global__ __launch_bounds__(256) void proj_kernel_fb(
    const float* __restrict__ vol, const float* __restrict__ poses,
    const int* __restrict__ idx, float* __restrict__ out)
{
    const int gj = blockIdx.x * 64 + (threadIdx.x & 63);
    const int gi = blockIdx.y * 4 + (threadIdx.x >> 6);
    const int j  = blockIdx.z;
    if (blockIdx.x == 0 && blockIdx.y == 0 && j == 0 && threadIdx.x < NPROJ)
        out[OUT_PROJ + threadIdx.x] = (float)idx[threadIdx.x];
    if (gi >= RES || gj >= RES) return;
    const int pid = idx[j];
    const float ex = poses[pid*3+0], ey = poses[pid*3+1], ez = poses[pid*3+2];
    const float pdx = (float)gi - 89.5f, pdz = (float)gj - 89.5f;
    const float inv_ey = 1.0f / ey;
    const float sx = (ex - pdx) * inv_ey, sz = (ez - pdz) * inv_ey;
    const float ddx = pdx - ex, ddz = pdz - ez;
    const float dxw = sqrtf(ddx*ddx + ey*ey + ddz*ddz) * fabsf(inv_ey);
    const float cb = pdx + 63.5f, ab = pdz + 63.5f;
    float acc = 0.0f;
    for (int p = 0; p < DVOL; ++p) {
        const float cf = fmaf((float)p, sx, cb);
        const float af = fmaf((float)p, sz, ab);
        if (cf >= -1.0f && cf < 128.0f && af >= -1.0f && af < 128.0f) {
            const float c0f = floorf(cf), a0f = floorf(af);
            const float tc = cf - c0f, ta = af - a0f;
            const int c0 = (int)c0f, a0 = (int)a0f;
            const float wc0 = (c0 >= 0)   ? (1.0f - tc) : 0.0f;
            const float wc1 = (c0 <= 126) ? tc          : 0.0f;
            const float wa0 = (a0 >= 0)   ? (1.0f - ta) : 0.0f;
            const float wa1 = (a0 <= 126) ? ta          : 0.0f;
            const int c0c = c0 < 0 ? 0 : c0;
            const int c1c = c0 >= 127 ? 127 : c0 + 1;
            const int a0c = a0 < 0 ? 0 : a0;
            const int a1c = a0 >= 127 ? 127 : a0 + 1;
            const float w00 = wc0*wa0, w01 = wc0*wa1, w10 = wc1*wa0, w11 = wc1*wa1;
            const int b0 = (c0c << 14) + (p << 7);
            const int b1 = (c1c << 14) + (p << 7);
            float s = w00*vol[b0+a0c] + w01*vol[b0+a1c] + w10*vol[b1+a0c] + w11*vol[b1+a1c];
            if (p >= 1)
                s += w00*vol[b0+a0c-128] + w01*vol[b0+a1c-128]
                   + w10*vol[b1+a0c-128] + w11*vol[b1+a1c-128];
            acc += 0.5f * s;
        }
    }
    out[j * (RES * RES) + gi * RES + gj] = acc * dxw;
}

extern "C" void kernel_launch(void* const* d_in, const int* in_sizes, int n_in,
                              void* d_out, int out_size, void* d_ws, size_t ws_size,
                              hipStream_t stream) {
    const float* vol   = (const float*)d_in[0];
    const float* poses = (const float*)d_in[1];
    const int*   idx   = (const int*)d_in[2];
    float* out = (float*)d_out;

    if (ws_size >= (size_t)IL_TOT * sizeof(uint32_t)) {
        uint32_t* ilbuf = (uint32_t*)d_ws;
        dim3 pgrid(8, DVOL);                                        // (word-range, p)
        pad_kernel<<<pgrid, 128, 0, stream>>>(vol, ilbuf);
        dim3 grid(3 /*ceil(179/64)*/, 90 /*ceil(179/2)*/, NPROJ);   // R10/R15-proven
        proj_fast<<<grid, 128, 0, stream>>>(ilbuf, poses, idx, out);
    } else {
        dim3 grid(3, 45, NPROJ);
        proj_kernel_fb<<<grid, 256, 0, stream>>>(vol, poses, idx, out);
    }
}